// Round 1
// baseline (92.990 us; speedup 1.0000x reference)
//
#include <hip/hip_runtime.h>

// MonotoneActivation: B=4096, G=512, K=4, D=8
// out[b, g*8+d] = sum_j coef_j * params[g, idx_j, d]
// Round 4 (polish):
//  - r0 == 15 always -> hoist that gather out of the loop (4 -> 3 LDS reads/iter)
//  - LDS param layout per g changed from [r][h] to [h][r]: data-dependent gather
//    start-bank-group becomes (g_l + r) & 7; measured r-value sets
//    (r1 in {14,13,11,7}, r3 in {1,2,4,8}) now map to distinct groups mod 8
//    instead of colliding via the old 2r term -> fewer bank conflicts.
//  - all NB X-loads prefetched into registers before the compute loop so the
//    global-load latency never stacks on the sort -> gather dependent chain.
//  - non-temporal stores for the 67 MB streaming output (skip L2 allocation).

#define BB 4096
#define GG 512
#define G_TILE 16
#define NB 8            // 8 b-rows per iter * NB iters -> 64 b per block
#define G_STRIDE 33     // float4 per g in LDS (32 + 1 pad)

typedef float f32x4 __attribute__((ext_vector_type(4)));

__global__ __launch_bounds__(256) void monoact_kernel(
    const float4* __restrict__ X4,   // (B, 512) float4 view of X (B, 2048) fp32
    const float4* __restrict__ P4,   // (G, 32) float4 view of params (G,16,8) fp32
    float4* __restrict__ O4)         // (B, 1024) float4 view of out (B, 4096) fp32
{
    __shared__ float4 lds_p[G_TILE * G_STRIDE];   // 8448 B

    const int tid = threadIdx.x;
    const int g0 = blockIdx.x * G_TILE;
    const int b0 = blockIdx.y * (8 * NB);

    // Stage params[g0..g0+15] into LDS with per-g layout [h][r] (h = D-half).
    // Slot index within a g block is rem = h*16 + r; source float4 within the
    // g block is r*2 + h. One-time 8 KB stage, L2-served.
    for (int j = tid; j < G_TILE * 32; j += 256) {
        const int g_l = j >> 5;
        const int rem = j & 31;          // rem = h*16 + r
        const int h_s = rem >> 4;
        const int r_s = rem & 15;
        lds_p[g_l * G_STRIDE + rem] = P4[(g0 + g_l) * 32 + r_s * 2 + h_s];
    }
    __syncthreads();

    const int gh  = tid & 31;        // g_l*2 + h
    const int g_l = gh >> 1;
    const int h   = gh & 1;          // which D-half (float4) of the output row
    const int b_l = tid >> 5;        // 0..7
    const int g = g0 + g_l;
    const float4* __restrict__ pg = lds_p + g_l * G_STRIDE + h * 16;

    // r0 == 15 for every sample: loop-invariant gather, keep in registers.
    const float4 aTop = pg[15];

    // Prefetch all NB X values (addresses are compile-time-known per iter).
    float4 xr[NB];
#pragma unroll
    for (int it = 0; it < NB; ++it) {
        xr[it] = X4[(b0 + it * 8 + b_l) * 512 + g];
    }

#pragma unroll
    for (int it = 0; it < NB; ++it) {
        const int b = b0 + it * 8 + b_l;
        const float4 x = xr[it];

        float v[4] = {x.x, x.y, x.z, x.w};
        int   id[4] = {0, 1, 2, 3};
#define CSWAP(a, c)                                               \
        {                                                         \
            bool sw = v[a] > v[c];                                \
            float tv = sw ? v[a] : v[c];                          \
            v[a] = sw ? v[c] : v[a];                              \
            v[c] = tv;                                            \
            int ti = sw ? id[a] : id[c];                          \
            id[a] = sw ? id[c] : id[a];                           \
            id[c] = ti;                                           \
        }
        CSWAP(0, 1)
        CSWAP(2, 3)
        CSWAP(0, 2)
        CSWAP(1, 3)
        CSWAP(1, 2)
#undef CSWAP

        const float c0 = v[0];
        const float c1 = v[1] - v[0];
        const float c2 = v[2] - v[1];
        const float c3 = v[3] - v[2];

        // r0 = 15 (hoisted). r3 = 15 - 2^id0 - 2^id1 - 2^id2 = 2^id3.
        const int r1 = 15 - (1 << id[0]);
        const int r2 = r1 - (1 << id[1]);
        const int r3 = 1 << id[3];

        const float4 a1 = pg[r1];
        const float4 a2 = pg[r2];
        const float4 a3 = pg[r3];

        float4 o;
        o.x = fmaf(c0, aTop.x, fmaf(c1, a1.x, fmaf(c2, a2.x, c3 * a3.x)));
        o.y = fmaf(c0, aTop.y, fmaf(c1, a1.y, fmaf(c2, a2.y, c3 * a3.y)));
        o.z = fmaf(c0, aTop.z, fmaf(c1, a1.z, fmaf(c2, a2.z, c3 * a3.z)));
        o.w = fmaf(c0, aTop.w, fmaf(c1, a1.w, fmaf(c2, a2.w, c3 * a3.w)));

        // 32 consecutive lanes -> 512 B fully-dense contiguous store per b-row.
        // Streaming output: non-temporal, don't allocate in L2.
        __builtin_nontemporal_store(*(const f32x4*)&o,
                                    (f32x4*)&O4[b * 1024 + g0 * 2 + gh]);
    }
}

extern "C" void kernel_launch(void* const* d_in, const int* in_sizes, int n_in,
                              void* d_out, int out_size, void* d_ws, size_t ws_size,
                              hipStream_t stream) {
    const float4* X4 = (const float4*)d_in[0];   // X: (4096, 2048) fp32
    const float4* P4 = (const float4*)d_in[1];   // params: (512, 16, 8) fp32
    float4* O4 = (float4*)d_out;                 // out: (4096, 4096) fp32

    dim3 grid(GG / G_TILE, BB / (8 * NB));       // (32, 64) = 2048 blocks
    monoact_kernel<<<grid, 256, 0, stream>>>(X4, P4, O4);
}